// Round 5
// baseline (630.083 us; speedup 1.0000x reference)
//
#include <hip/hip_runtime.h>
#include <stdint.h>

typedef __attribute__((ext_vector_type(4))) float f32x4;
typedef __attribute__((ext_vector_type(8))) short s16x8;
typedef __attribute__((ext_vector_type(8))) unsigned short us8;

__device__ __forceinline__ float bf2f(unsigned short u){
  union { unsigned int i; float f; } v; v.i = ((unsigned int)u) << 16; return v.f;
}
__device__ __forceinline__ unsigned short f2bf(float f){
  union { float f; unsigned int i; } v; v.f = f;
  unsigned int r = v.i + 0x7FFFu + ((v.i >> 16) & 1u);
  return (unsigned short)(r >> 16);
}
__device__ __forceinline__ float sigm(float x){ return 1.0f / (1.0f + __expf(-x)); }

// ---------------- K0: prep ----------------
// WoutP padded to 10240 rows (640 16-col tiles) so pass-2 chunks of 256 cols
// never index OOB; pad bias = -1e30 -> exp contributes 0, outputs guarded.
#define NA (10240*128)
#define NB 10240
#define ND 512
#define NE (256*64)
#define NF 32768

__global__ void k_prep(const float* __restrict__ Wout, const float* __restrict__ bout,
                       const float* __restrict__ bih,  const float* __restrict__ bhh,
                       const float* __restrict__ tobj, const float* __restrict__ Wtgt,
                       const float* __restrict__ btgt,
                       const float* __restrict__ ceWih, const float* __restrict__ ceWhh,
                       unsigned short* __restrict__ WoutP, float* __restrict__ boutP,
                       float* __restrict__ bsum, float* __restrict__ tgt,
                       unsigned short* __restrict__ cePack)
{
  int tid = blockIdx.x * 256 + threadIdx.x;
  if (tid < NA){
    int vv = tid >> 7, k = tid & 127;
    float val = (vv < 10001) ? Wout[vv*128 + k] : 0.0f;
    WoutP[tid] = f2bf(val);
  } else if (tid < NA+NB){
    int vv = tid - NA;
    boutP[vv] = (vv < 10001) ? bout[vv] : -1e30f;
  } else if (tid < NA+NB+ND){
    int g = tid - NA - NB;
    bsum[g] = bih[g] + bhh[g];
  } else if (tid < NA+NB+ND+NE){
    int i = tid - NA - NB - ND; int b = i >> 6, j = i & 63;
    const float* to = tobj + b*4; const float* wt = Wtgt + j*4;
    tgt[i] = btgt[j] + to[0]*wt[0] + to[1]*wt[1] + to[2]*wt[2] + to[3]*wt[3];
  } else if (tid < NA+NB+ND+NE+NF){
    // bf16-pack ce weights, pre-XOR-swizzled in 8-elem slots for conflict-free LDS reads
    int i = tid - NA - NB - ND - NE;
    int half = i >> 14;
    int r = (i >> 6) & 255;
    int k = i & 63;
    int k8 = k >> 3;
    int slot = ((k8 ^ (r & 7)) << 3) | (k & 7);
    const float* src = half ? ceWhh : ceWih;
    cePack[half*16384 + r*64 + slot] = f2bf(src[r*64 + k]);
  }
}

// ---------------- K1: canvas encoder (25-step LSTM, H=64) ----------------
__global__ __launch_bounds__(256) void k_canvas(
    const float* __restrict__ prevC, const float* __restrict__ finC,
    const float* __restrict__ Wobj,  const float* __restrict__ bobj,
    const unsigned short* __restrict__ cePack,
    const float* __restrict__ cebih, const float* __restrict__ cebhh,
    float* __restrict__ encP, float* __restrict__ encF)
{
  __shared__ unsigned short wih[256*64] __attribute__((aligned(16)));
  __shared__ unsigned short whh[256*64] __attribute__((aligned(16)));
  __shared__ float seq[25*4];
  __shared__ float xb[64] __attribute__((aligned(16)));
  __shared__ float hb[2][64] __attribute__((aligned(16)));
  __shared__ float gates[256];
  __shared__ float wobj_s[256];
  __shared__ float bobj_s[64];
  __shared__ float bsum_ce[256];

  int tid = threadIdx.x;
  int b = blockIdx.x & 255;
  int which = blockIdx.x >> 8;
  const float* canvas = (which ? finC : prevC) + b*100;

  // pure 16B copies: cePack is already bf16 + swizzled
  {
    const us8* cp = (const us8*)cePack;
    us8* wl = (us8*)wih;
    us8* hl = (us8*)whh;
    for (int i = tid; i < 2048; i += 256){
      wl[i] = cp[i];
      hl[i] = cp[2048 + i];
    }
  }
  wobj_s[tid] = Wobj[tid];
  if (tid < 64) bobj_s[tid] = bobj[tid];
  bsum_ce[tid] = cebih[tid] + cebhh[tid];
  if (tid < 64) hb[0][tid] = 0.0f;
  if (tid == 0){
    int pos = 0;
    for (int i = 0; i < 25; i++){
      float a0=canvas[i*4+0], a1=canvas[i*4+1], a2=canvas[i*4+2], a3=canvas[i*4+3];
      if (a0+a1+a2+a3 >= 0.0f){
        seq[pos*4+0]=a0; seq[pos*4+1]=a1; seq[pos*4+2]=a2; seq[pos*4+3]=a3; pos++;
      }
    }
    for (; pos < 25; pos++){
      seq[pos*4+0]=-1.0f; seq[pos*4+1]=-1.0f; seq[pos*4+2]=-1.0f; seq[pos*4+3]=-1.0f;
    }
  }
  __syncthreads();

  float creg = 0.0f;
  int cur = 0;
  const float4* x4 = (const float4*)xb;

  for (int t = 0; t < 25; t++){
    if (tid < 64){
      float a = bobj_s[tid];
      a += wobj_s[tid*4+0]*seq[t*4+0] + wobj_s[tid*4+1]*seq[t*4+1]
         + wobj_s[tid*4+2]*seq[t*4+2] + wobj_s[tid*4+3]*seq[t*4+3];
      xb[tid] = a;
    }
    __syncthreads();
    float acc = bsum_ce[tid];
    const float4* h4 = (const float4*)hb[cur];
    int rowoff = tid*64;
    int sw = tid & 7;
    #pragma unroll
    for (int k8 = 0; k8 < 8; k8++){
      int slot = ((k8 ^ sw) * 8);
      us8 w1 = *reinterpret_cast<const us8*>(&wih[rowoff + slot]);
      us8 w2 = *reinterpret_cast<const us8*>(&whh[rowoff + slot]);
      float4 xa = x4[2*k8], xc = x4[2*k8+1];
      float4 ha = h4[2*k8], hc = h4[2*k8+1];
      acc += bf2f(w1[0])*xa.x + bf2f(w1[1])*xa.y + bf2f(w1[2])*xa.z + bf2f(w1[3])*xa.w;
      acc += bf2f(w1[4])*xc.x + bf2f(w1[5])*xc.y + bf2f(w1[6])*xc.z + bf2f(w1[7])*xc.w;
      acc += bf2f(w2[0])*ha.x + bf2f(w2[1])*ha.y + bf2f(w2[2])*ha.z + bf2f(w2[3])*ha.w;
      acc += bf2f(w2[4])*hc.x + bf2f(w2[5])*hc.y + bf2f(w2[6])*hc.z + bf2f(w2[7])*hc.w;
    }
    gates[tid] = acc;
    __syncthreads();
    if (tid < 64){
      float i_ = sigm(gates[tid]);
      float f_ = sigm(gates[64+tid]);
      float g_ = tanhf(gates[128+tid]);
      float o_ = sigm(gates[192+tid]);
      creg = f_*creg + i_*g_;
      hb[cur^1][tid] = o_ * tanhf(creg);
    }
    __syncthreads();
    cur ^= 1;
  }
  if (tid < 64){
    (which ? encF : encP)[b*64 + tid] = hb[cur][tid];
  }
}

// ---------------- K2: main LSTM recurrence (66 steps, H=128), Wih fused ----------------
__global__ __launch_bounds__(512, 2) void k_rec(
    const float* __restrict__ Whh, const float* __restrict__ Wih,
    const float* __restrict__ bsum, const int* __restrict__ inst,
    const float* __restrict__ embW, const float* __restrict__ tgt,
    const float* __restrict__ encP, const float* __restrict__ encF,
    unsigned short* __restrict__ Hout)
{
  int b = blockIdx.x;
  int g = threadIdx.x;
  __shared__ float xb[2][64] __attribute__((aligned(16)));
  __shared__ float hb[2][128] __attribute__((aligned(16)));
  __shared__ float gates[512];

  float wreg[128];
  float ureg[64];
  {
    const float4* wrow = (const float4*)(Whh + g*128);
    #pragma unroll
    for (int k4 = 0; k4 < 32; k4++){
      float4 w = wrow[k4];
      wreg[4*k4+0]=w.x; wreg[4*k4+1]=w.y; wreg[4*k4+2]=w.z; wreg[4*k4+3]=w.w;
    }
    const float4* urow = (const float4*)(Wih + g*64);
    #pragma unroll
    for (int k4 = 0; k4 < 16; k4++){
      float4 w = urow[k4];
      ureg[4*k4+0]=w.x; ureg[4*k4+1]=w.y; ureg[4*k4+2]=w.z; ureg[4*k4+3]=w.w;
    }
  }
  float bz = bsum[g];
  float creg = 0.0f;
  if (g < 128) hb[0][g] = 0.0f;
  if (g < 64)  xb[0][g] = encP[b*64+g] + encF[b*64+g];
  int cur = 0;
  __syncthreads();

  for (int s = 0; s < 66; s++){
    float a0 = bz, a1 = 0.0f, a2 = 0.0f, a3 = 0.0f;
    const float4* h4 = (const float4*)hb[cur];
    const float4* x4 = (const float4*)xb[cur];
    #pragma unroll
    for (int k4 = 0; k4 < 32; k4 += 4){
      float4 h0 = h4[k4], h1 = h4[k4+1], h2 = h4[k4+2], h3 = h4[k4+3];
      a0 += wreg[4*k4+0]*h0.x + wreg[4*k4+1]*h0.y + wreg[4*k4+2]*h0.z + wreg[4*k4+3]*h0.w;
      a1 += wreg[4*k4+4]*h1.x + wreg[4*k4+5]*h1.y + wreg[4*k4+6]*h1.z + wreg[4*k4+7]*h1.w;
      a2 += wreg[4*k4+8]*h2.x + wreg[4*k4+9]*h2.y + wreg[4*k4+10]*h2.z + wreg[4*k4+11]*h2.w;
      a3 += wreg[4*k4+12]*h3.x + wreg[4*k4+13]*h3.y + wreg[4*k4+14]*h3.z + wreg[4*k4+15]*h3.w;
    }
    #pragma unroll
    for (int k4 = 0; k4 < 16; k4 += 4){
      float4 x0 = x4[k4], x1 = x4[k4+1], x2 = x4[k4+2], x3 = x4[k4+3];
      a0 += ureg[4*k4+0]*x0.x + ureg[4*k4+1]*x0.y + ureg[4*k4+2]*x0.z + ureg[4*k4+3]*x0.w;
      a1 += ureg[4*k4+4]*x1.x + ureg[4*k4+5]*x1.y + ureg[4*k4+6]*x1.z + ureg[4*k4+7]*x1.w;
      a2 += ureg[4*k4+8]*x2.x + ureg[4*k4+9]*x2.y + ureg[4*k4+10]*x2.z + ureg[4*k4+11]*x2.w;
      a3 += ureg[4*k4+12]*x3.x + ureg[4*k4+13]*x3.y + ureg[4*k4+14]*x3.z + ureg[4*k4+15]*x3.w;
    }
    gates[g] = (a0 + a1) + (a2 + a3);
    __syncthreads();
    if (g < 128){
      float i_ = sigm(gates[g]);
      float f_ = sigm(gates[128+g]);
      float g_ = tanhf(gates[256+g]);
      float o_ = sigm(gates[384+g]);
      creg = f_*creg + i_*g_;
      float h = o_ * tanhf(creg);
      hb[cur^1][g] = h;
      if (s >= 2) Hout[((s-2)*256 + b)*128 + g] = f2bf(h);
    } else if (g < 192 && s < 65){
      int l = g - 128;
      float v;
      if (s + 1 == 1) v = tgt[b*64 + l];
      else { int tok = inst[b*65 + (s - 1)]; v = embW[tok*64 + l]; }
      xb[cur^1][l] = v;
    }
    __syncthreads();
    cur ^= 1;
  }
}

// ---------------- K3: logits GEMM + log_softmax ----------------
// 512 blocks (64 t x 8 row-octets of 32 rows), 8 waves. Pass 1: row sums of exp.
// Pass 2: 40 chunks of 256 cols; per chunk each wave computes 2 tiles (32 rows),
// stages into dyn-LDS [2][32][258], writes 1KB-contiguous-per-row nt-stores.
// B-tile loads always issued BEFORE the store phase so vmcnt waits never drain
// fresh stores (FIFO vmcnt semantics).
#define ROWSTR ((size_t)64*10001)

__global__ __launch_bounds__(512, 4) void k_out(
    const unsigned short* __restrict__ Hout, const unsigned short* __restrict__ WoutP,
    const float* __restrict__ boutP, float* __restrict__ out)
{
  extern __shared__ float stage[];   // [2][32][258] floats = 66048 B
  __shared__ float rs_l[8][32];
  __shared__ float lse_l[32];

  int blk = blockIdx.x;
  int t = blk >> 3;
  int b0 = (blk & 7) * 32;
  int r0 = t*256 + b0;
  int tid = threadIdx.x;
  int w = tid >> 6;
  int l = tid & 63;
  int lm = l & 15;
  int lq = l >> 4;
  int kof = lq * 8;
  size_t obase = ((size_t)b0*64 + (size_t)t)*10001u;

  // A fragments: 32 rows (two 16-row chains), full K=128, in registers
  s16x8 af0[4], af1[4];
  {
    const s16x8* ap0 = (const s16x8*)(Hout + (size_t)(r0 + lm)*128 + kof);
    const s16x8* ap1 = (const s16x8*)(Hout + (size_t)(r0 + 16 + lm)*128 + kof);
    #pragma unroll
    for (int kk = 0; kk < 4; kk++){ af0[kk] = ap0[kk*4]; af1[kk] = ap1[kk*4]; }
  }

  s16x8 c0A[4], c0B[4], c1A[4], c1B[4];
#define LOADB(dst, tl) { \
    const s16x8* bp_ = (const s16x8*)(WoutP + (size_t)((tl)*16 + lm)*128 + kof); \
    dst[0] = bp_[0]; dst[1] = bp_[4]; dst[2] = bp_[8]; dst[3] = bp_[12]; }

  // ---- pass 1: row sums of exp(logit), 80 tiles per wave (incl. zero-pad tiles) ----
  float rs0[4] = {0,0,0,0}, rs1[4] = {0,0,0,0};
#define P1COMP(buf, tl) { \
    f32x4 a0_ = {0,0,0,0}, a1_ = {0,0,0,0}; \
    _Pragma("unroll") \
    for (int kk = 0; kk < 4; kk++){ \
      a0_ = __builtin_amdgcn_mfma_f32_16x16x32_bf16(af0[kk], buf[kk], a0_, 0, 0, 0); \
      a1_ = __builtin_amdgcn_mfma_f32_16x16x32_bf16(af1[kk], buf[kk], a1_, 0, 0, 0); } \
    float bo_ = boutP[(tl)*16 + lm]; \
    _Pragma("unroll") \
    for (int i = 0; i < 4; i++){ rs0[i] += __expf(a0_[i] + bo_); rs1[i] += __expf(a1_[i] + bo_); } }

  {
    int tl = w;
    LOADB(c0A, tl);
    for (int it = 0; it < 39; it++){
      LOADB(c0B, tl + 8);
      P1COMP(c0A, tl);
      LOADB(c0A, tl + 16);
      P1COMP(c0B, tl + 8);
      tl += 16;
    }
    LOADB(c0B, tl + 8);
    P1COMP(c0A, tl);        // tile w + 624
    P1COMP(c0B, tl + 8);    // tile w + 632
  }

  #pragma unroll
  for (int i = 0; i < 4; i++){
    float s0 = rs0[i], s1 = rs1[i];
    s0 += __shfl_xor(s0, 1); s0 += __shfl_xor(s0, 2); s0 += __shfl_xor(s0, 4); s0 += __shfl_xor(s0, 8);
    s1 += __shfl_xor(s1, 1); s1 += __shfl_xor(s1, 2); s1 += __shfl_xor(s1, 4); s1 += __shfl_xor(s1, 8);
    rs0[i] = s0; rs1[i] = s1;
  }
  if (lm == 0){
    #pragma unroll
    for (int i = 0; i < 4; i++){
      rs_l[w][lq*4 + i] = rs0[i];
      rs_l[w][16 + lq*4 + i] = rs1[i];
    }
  }
  __syncthreads();
  if (tid < 32){
    float s = rs_l[0][tid] + rs_l[1][tid] + rs_l[2][tid] + rs_l[3][tid]
            + rs_l[4][tid] + rs_l[5][tid] + rs_l[6][tid] + rs_l[7][tid];
    lse_l[tid] = logf(s);
  }
  __syncthreads();
  float ml0[4], ml1[4];
  #pragma unroll
  for (int i = 0; i < 4; i++){ ml0[i] = lse_l[lq*4 + i]; ml1[i] = lse_l[16 + lq*4 + i]; }

  // ---- pass 2 ----
  int colA = w*16 + lm;
#define P2COMP2(bufA, bufB, c) { \
    f32x4 p0_ = {0,0,0,0}, p1_ = {0,0,0,0}, q0_ = {0,0,0,0}, q1_ = {0,0,0,0}; \
    _Pragma("unroll") \
    for (int kk = 0; kk < 4; kk++){ \
      p0_ = __builtin_amdgcn_mfma_f32_16x16x32_bf16(af0[kk], bufA[kk], p0_, 0, 0, 0); \
      p1_ = __builtin_amdgcn_mfma_f32_16x16x32_bf16(af1[kk], bufA[kk], p1_, 0, 0, 0); \
      q0_ = __builtin_amdgcn_mfma_f32_16x16x32_bf16(af0[kk], bufB[kk], q0_, 0, 0, 0); \
      q1_ = __builtin_amdgcn_mfma_f32_16x16x32_bf16(af1[kk], bufB[kk], q1_, 0, 0, 0); } \
    float boA_ = boutP[((c)*16 + w)*16 + lm]; \
    float boB_ = boutP[((c)*16 + 8 + w)*16 + lm]; \
    float* sb_ = stage + ((c)&1)*(32*258); \
    _Pragma("unroll") \
    for (int i = 0; i < 4; i++){ \
      sb_[(lq*4+i)*258 + colA]        = p0_[i] + boA_ - ml0[i]; \
      sb_[(16+lq*4+i)*258 + colA]     = p1_[i] + boA_ - ml1[i]; \
      sb_[(lq*4+i)*258 + 128 + colA]  = q0_[i] + boB_ - ml0[i]; \
      sb_[(16+lq*4+i)*258 + 128 + colA] = q1_[i] + boB_ - ml1[i]; } }

#define BAR() { asm volatile("s_waitcnt lgkmcnt(0)" ::: "memory"); __builtin_amdgcn_s_barrier(); }

#define WPHASE(c) { \
    const float* sb_ = stage + ((c)&1)*(32*258); \
    int vbase_ = (c)*256; \
    if ((c) < 39){ \
      _Pragma("unroll") \
      for (int j = 0; j < 16; j++){ \
        int e_ = j*512 + tid; int row_ = e_ >> 8; int cc_ = e_ & 255; \
        __builtin_nontemporal_store(sb_[row_*258 + cc_], &out[obase + (size_t)row_*ROWSTR + (unsigned)(vbase_ + cc_)]); } \
    } else { \
      _Pragma("unroll") \
      for (int j = 0; j < 16; j++){ \
        int e_ = j*512 + tid; int row_ = e_ >> 8; int cc_ = e_ & 255; \
        if (vbase_ + cc_ < 10001) \
          __builtin_nontemporal_store(sb_[row_*258 + cc_], &out[obase + (size_t)row_*ROWSTR + (unsigned)(vbase_ + cc_)]); } } }

  LOADB(c0A, w); LOADB(c0B, 8 + w);
  for (int cp = 0; cp < 20; cp++){
    int c = cp*2;
    P2COMP2(c0A, c0B, c);
    LOADB(c1A, (c+1)*16 + w); LOADB(c1B, (c+1)*16 + 8 + w);
    BAR();
    WPHASE(c);
    P2COMP2(c1A, c1B, c+1);
    if (c + 2 < 40){ LOADB(c0A, (c+2)*16 + w); LOADB(c0B, (c+2)*16 + 8 + w); }
    BAR();
    WPHASE(c+1);
  }
}

// ---------------- host launcher ----------------
extern "C" void kernel_launch(void* const* d_in, const int* in_sizes, int n_in,
                              void* d_out, int out_size, void* d_ws, size_t ws_size,
                              hipStream_t stream)
{
  (void)in_sizes; (void)n_in; (void)out_size; (void)ws_size;
  const int*   inst    = (const int*)  d_in[0];
  const float* prevC   = (const float*)d_in[1];
  const float* finC    = (const float*)d_in[2];
  const float* tobj    = (const float*)d_in[3];
  const float* embW    = (const float*)d_in[4];
  const float* Wih     = (const float*)d_in[5];
  const float* Whh     = (const float*)d_in[6];
  const float* bih     = (const float*)d_in[7];
  const float* bhh     = (const float*)d_in[8];
  const float* Wout    = (const float*)d_in[9];
  const float* bout    = (const float*)d_in[10];
  const float* Wtgt    = (const float*)d_in[11];
  const float* btgt    = (const float*)d_in[12];
  const float* Wobj    = (const float*)d_in[13];
  const float* bobj    = (const float*)d_in[14];
  const float* ceWih   = (const float*)d_in[15];
  const float* ceWhh   = (const float*)d_in[16];
  const float* cebih   = (const float*)d_in[17];
  const float* cebhh   = (const float*)d_in[18];

  char* ws = (char*)d_ws;
  unsigned short* WoutP = (unsigned short*)(ws + 0);         // 10240*128*2 = 2,621,440
  float* boutP = (float*)(ws + 2621440);                     // 10240*4     = 40,960
  float* bsum  = (float*)(ws + 2662400);                     // 512*4       = 2,048
  float* tgt   = (float*)(ws + 2664448);                     // 256*64*4    = 65,536
  float* encP  = (float*)(ws + 2729984);                     // 256*64*4    = 65,536
  float* encF  = (float*)(ws + 2795520);                     // 256*64*4    = 65,536
  unsigned short* Hout = (unsigned short*)(ws + 2861056);    // 64*256*128*2 = 4,194,304
  unsigned short* cePack = (unsigned short*)(ws + 7055360);  // 32768*2     = 65,536
  // total ws use: 7,120,896 bytes (~7.1 MB)
  float* out = (float*)d_out;

  hipFuncSetAttribute((const void*)k_out,
                      hipFuncAttributeMaxDynamicSharedMemorySize, 66048);

  k_prep  <<<5354, 256, 0, stream>>>(Wout, bout, bih, bhh, tobj, Wtgt, btgt,
                                     ceWih, ceWhh, WoutP, boutP, bsum, tgt, cePack);
  k_canvas<<<512, 256, 0, stream>>>(prevC, finC, Wobj, bobj, cePack,
                                    cebih, cebhh, encP, encF);
  k_rec   <<<256, 512, 0, stream>>>(Whh, Wih, bsum, inst, embW, tgt, encP, encF, Hout);
  k_out   <<<512, 512, 66048, stream>>>(Hout, WoutP, boutP, out);
}

// Round 6
// 624.541 us; speedup vs baseline: 1.0089x; 1.0089x over previous
//
#include <hip/hip_runtime.h>
#include <stdint.h>

typedef __attribute__((ext_vector_type(4))) float f32x4;
typedef __attribute__((ext_vector_type(8))) short s16x8;
typedef __attribute__((ext_vector_type(8))) unsigned short us8;

__device__ __forceinline__ float bf2f(unsigned short u){
  union { unsigned int i; float f; } v; v.i = ((unsigned int)u) << 16; return v.f;
}
__device__ __forceinline__ unsigned short f2bf(float f){
  union { float f; unsigned int i; } v; v.f = f;
  unsigned int r = v.i + 0x7FFFu + ((v.i >> 16) & 1u);
  return (unsigned short)(r >> 16);
}
__device__ __forceinline__ float sigm(float x){ return 1.0f / (1.0f + __expf(-x)); }

// ---------------- K0: prep ----------------
#define NA (10240*128)
#define NB 10240
#define ND 512
#define NE (256*64)
#define NF 32768

__global__ void k_prep(const float* __restrict__ Wout, const float* __restrict__ bout,
                       const float* __restrict__ bih,  const float* __restrict__ bhh,
                       const float* __restrict__ tobj, const float* __restrict__ Wtgt,
                       const float* __restrict__ btgt,
                       const float* __restrict__ ceWih, const float* __restrict__ ceWhh,
                       unsigned short* __restrict__ WoutP, float* __restrict__ boutP,
                       float* __restrict__ bsum, float* __restrict__ tgt,
                       unsigned short* __restrict__ cePack)
{
  int tid = blockIdx.x * 256 + threadIdx.x;
  if (tid < NA){
    int vv = tid >> 7, k = tid & 127;
    float val = (vv < 10001) ? Wout[vv*128 + k] : 0.0f;
    WoutP[tid] = f2bf(val);
  } else if (tid < NA+NB){
    int vv = tid - NA;
    boutP[vv] = (vv < 10001) ? bout[vv] : -1e30f;
  } else if (tid < NA+NB+ND){
    int g = tid - NA - NB;
    bsum[g] = bih[g] + bhh[g];
  } else if (tid < NA+NB+ND+NE){
    int i = tid - NA - NB - ND; int b = i >> 6, j = i & 63;
    const float* to = tobj + b*4; const float* wt = Wtgt + j*4;
    tgt[i] = btgt[j] + to[0]*wt[0] + to[1]*wt[1] + to[2]*wt[2] + to[3]*wt[3];
  } else if (tid < NA+NB+ND+NE+NF){
    int i = tid - NA - NB - ND - NE;
    int half = i >> 14;
    int r = (i >> 6) & 255;
    int k = i & 63;
    int k8 = k >> 3;
    int slot = ((k8 ^ (r & 7)) << 3) | (k & 7);
    const float* src = half ? ceWhh : ceWih;
    cePack[half*16384 + r*64 + slot] = f2bf(src[r*64 + k]);
  }
}

// ---------------- K1: canvas encoder (25-step LSTM, H=64) ----------------
__global__ __launch_bounds__(256) void k_canvas(
    const float* __restrict__ prevC, const float* __restrict__ finC,
    const float* __restrict__ Wobj,  const float* __restrict__ bobj,
    const unsigned short* __restrict__ cePack,
    const float* __restrict__ cebih, const float* __restrict__ cebhh,
    float* __restrict__ encP, float* __restrict__ encF)
{
  __shared__ unsigned short wih[256*64] __attribute__((aligned(16)));
  __shared__ unsigned short whh[256*64] __attribute__((aligned(16)));
  __shared__ float seq[25*4];
  __shared__ float xb[64] __attribute__((aligned(16)));
  __shared__ float hb[2][64] __attribute__((aligned(16)));
  __shared__ float gates[256];
  __shared__ float wobj_s[256];
  __shared__ float bobj_s[64];
  __shared__ float bsum_ce[256];

  int tid = threadIdx.x;
  int b = blockIdx.x & 255;
  int which = blockIdx.x >> 8;
  const float* canvas = (which ? finC : prevC) + b*100;

  {
    const us8* cp = (const us8*)cePack;
    us8* wl = (us8*)wih;
    us8* hl = (us8*)whh;
    for (int i = tid; i < 2048; i += 256){
      wl[i] = cp[i];
      hl[i] = cp[2048 + i];
    }
  }
  wobj_s[tid] = Wobj[tid];
  if (tid < 64) bobj_s[tid] = bobj[tid];
  bsum_ce[tid] = cebih[tid] + cebhh[tid];
  if (tid < 64) hb[0][tid] = 0.0f;
  if (tid == 0){
    int pos = 0;
    for (int i = 0; i < 25; i++){
      float a0=canvas[i*4+0], a1=canvas[i*4+1], a2=canvas[i*4+2], a3=canvas[i*4+3];
      if (a0+a1+a2+a3 >= 0.0f){
        seq[pos*4+0]=a0; seq[pos*4+1]=a1; seq[pos*4+2]=a2; seq[pos*4+3]=a3; pos++;
      }
    }
    for (; pos < 25; pos++){
      seq[pos*4+0]=-1.0f; seq[pos*4+1]=-1.0f; seq[pos*4+2]=-1.0f; seq[pos*4+3]=-1.0f;
    }
  }
  __syncthreads();

  float creg = 0.0f;
  int cur = 0;
  const float4* x4 = (const float4*)xb;

  for (int t = 0; t < 25; t++){
    if (tid < 64){
      float a = bobj_s[tid];
      a += wobj_s[tid*4+0]*seq[t*4+0] + wobj_s[tid*4+1]*seq[t*4+1]
         + wobj_s[tid*4+2]*seq[t*4+2] + wobj_s[tid*4+3]*seq[t*4+3];
      xb[tid] = a;
    }
    __syncthreads();
    float acc = bsum_ce[tid];
    const float4* h4 = (const float4*)hb[cur];
    int rowoff = tid*64;
    int sw = tid & 7;
    #pragma unroll
    for (int k8 = 0; k8 < 8; k8++){
      int slot = ((k8 ^ sw) * 8);
      us8 w1 = *reinterpret_cast<const us8*>(&wih[rowoff + slot]);
      us8 w2 = *reinterpret_cast<const us8*>(&whh[rowoff + slot]);
      float4 xa = x4[2*k8], xc = x4[2*k8+1];
      float4 ha = h4[2*k8], hc = h4[2*k8+1];
      acc += bf2f(w1[0])*xa.x + bf2f(w1[1])*xa.y + bf2f(w1[2])*xa.z + bf2f(w1[3])*xa.w;
      acc += bf2f(w1[4])*xc.x + bf2f(w1[5])*xc.y + bf2f(w1[6])*xc.z + bf2f(w1[7])*xc.w;
      acc += bf2f(w2[0])*ha.x + bf2f(w2[1])*ha.y + bf2f(w2[2])*ha.z + bf2f(w2[3])*ha.w;
      acc += bf2f(w2[4])*hc.x + bf2f(w2[5])*hc.y + bf2f(w2[6])*hc.z + bf2f(w2[7])*hc.w;
    }
    gates[tid] = acc;
    __syncthreads();
    if (tid < 64){
      float i_ = sigm(gates[tid]);
      float f_ = sigm(gates[64+tid]);
      float g_ = tanhf(gates[128+tid]);
      float o_ = sigm(gates[192+tid]);
      creg = f_*creg + i_*g_;
      hb[cur^1][tid] = o_ * tanhf(creg);
    }
    __syncthreads();
    cur ^= 1;
  }
  if (tid < 64){
    (which ? encF : encP)[b*64 + tid] = hb[cur][tid];
  }
}

// ---------------- K2: main LSTM recurrence (66 steps, H=128), Wih fused -------
// Hout layout: row r = b*64 + (s-2)  (matches output row order), r*128 + g
__global__ __launch_bounds__(512, 2) void k_rec(
    const float* __restrict__ Whh, const float* __restrict__ Wih,
    const float* __restrict__ bsum, const int* __restrict__ inst,
    const float* __restrict__ embW, const float* __restrict__ tgt,
    const float* __restrict__ encP, const float* __restrict__ encF,
    unsigned short* __restrict__ Hout)
{
  int b = blockIdx.x;
  int g = threadIdx.x;
  __shared__ float xb[2][64] __attribute__((aligned(16)));
  __shared__ float hb[2][128] __attribute__((aligned(16)));
  __shared__ float gates[512];

  float wreg[128];
  float ureg[64];
  {
    const float4* wrow = (const float4*)(Whh + g*128);
    #pragma unroll
    for (int k4 = 0; k4 < 32; k4++){
      float4 w = wrow[k4];
      wreg[4*k4+0]=w.x; wreg[4*k4+1]=w.y; wreg[4*k4+2]=w.z; wreg[4*k4+3]=w.w;
    }
    const float4* urow = (const float4*)(Wih + g*64);
    #pragma unroll
    for (int k4 = 0; k4 < 16; k4++){
      float4 w = urow[k4];
      ureg[4*k4+0]=w.x; ureg[4*k4+1]=w.y; ureg[4*k4+2]=w.z; ureg[4*k4+3]=w.w;
    }
  }
  float bz = bsum[g];
  float creg = 0.0f;
  if (g < 128) hb[0][g] = 0.0f;
  if (g < 64)  xb[0][g] = encP[b*64+g] + encF[b*64+g];
  int cur = 0;
  __syncthreads();

  for (int s = 0; s < 66; s++){
    float a0 = bz, a1 = 0.0f, a2 = 0.0f, a3 = 0.0f;
    const float4* h4 = (const float4*)hb[cur];
    const float4* x4 = (const float4*)xb[cur];
    #pragma unroll
    for (int k4 = 0; k4 < 32; k4 += 4){
      float4 h0 = h4[k4], h1 = h4[k4+1], h2 = h4[k4+2], h3 = h4[k4+3];
      a0 += wreg[4*k4+0]*h0.x + wreg[4*k4+1]*h0.y + wreg[4*k4+2]*h0.z + wreg[4*k4+3]*h0.w;
      a1 += wreg[4*k4+4]*h1.x + wreg[4*k4+5]*h1.y + wreg[4*k4+6]*h1.z + wreg[4*k4+7]*h1.w;
      a2 += wreg[4*k4+8]*h2.x + wreg[4*k4+9]*h2.y + wreg[4*k4+10]*h2.z + wreg[4*k4+11]*h2.w;
      a3 += wreg[4*k4+12]*h3.x + wreg[4*k4+13]*h3.y + wreg[4*k4+14]*h3.z + wreg[4*k4+15]*h3.w;
    }
    #pragma unroll
    for (int k4 = 0; k4 < 16; k4 += 4){
      float4 x0 = x4[k4], x1 = x4[k4+1], x2 = x4[k4+2], x3 = x4[k4+3];
      a0 += ureg[4*k4+0]*x0.x + ureg[4*k4+1]*x0.y + ureg[4*k4+2]*x0.z + ureg[4*k4+3]*x0.w;
      a1 += ureg[4*k4+4]*x1.x + ureg[4*k4+5]*x1.y + ureg[4*k4+6]*x1.z + ureg[4*k4+7]*x1.w;
      a2 += ureg[4*k4+8]*x2.x + ureg[4*k4+9]*x2.y + ureg[4*k4+10]*x2.z + ureg[4*k4+11]*x2.w;
      a3 += ureg[4*k4+12]*x3.x + ureg[4*k4+13]*x3.y + ureg[4*k4+14]*x3.z + ureg[4*k4+15]*x3.w;
    }
    gates[g] = (a0 + a1) + (a2 + a3);
    __syncthreads();
    if (g < 128){
      float i_ = sigm(gates[g]);
      float f_ = sigm(gates[128+g]);
      float g_ = tanhf(gates[256+g]);
      float o_ = sigm(gates[384+g]);
      creg = f_*creg + i_*g_;
      float h = o_ * tanhf(creg);
      hb[cur^1][g] = h;
      if (s >= 2) Hout[((size_t)(b*64 + (s-2)))*128 + g] = f2bf(h);
    } else if (g < 192 && s < 65){
      int l = g - 128;
      float v;
      if (s + 1 == 1) v = tgt[b*64 + l];
      else { int tok = inst[b*65 + (s - 1)]; v = embW[tok*64 + l]; }
      xb[cur^1][l] = v;
    }
    __syncthreads();
    cur ^= 1;
  }
}

// ---------------- K3: logits GEMM + log_softmax ----------------
// 512 blocks, each owns 32 CONSECUTIVE output rows r0=blk*32 (contiguous
// 1.25 MB output region). Pass 1: row sums of exp over 640 tiles. Pass 2:
// 20 chunks of 512 cols; stage[32][516] single-buffered; write phase = dense
// 256B-per-instr nt-stores, 2KB contiguous span per row per chunk.
__global__ __launch_bounds__(512, 4) void k_out(
    const unsigned short* __restrict__ Hout, const unsigned short* __restrict__ WoutP,
    const float* __restrict__ boutP, float* __restrict__ out)
{
  extern __shared__ float stage[];   // [32][516] floats = 66048 B
  __shared__ float rs_l[8][32];
  __shared__ float lse_l[32];

  int blk = blockIdx.x;
  int r0 = blk * 32;
  int tid = threadIdx.x;
  int w = tid >> 6;
  int l = tid & 63;
  int lm = l & 15;
  int lq = l >> 4;
  int kof = lq * 8;
  size_t obase = (size_t)r0 * 10001u;

  // A fragments: rows r0+lm (chain 0) and r0+16+lm (chain 1), K=128
  s16x8 af0[4], af1[4];
  {
    const s16x8* ap0 = (const s16x8*)(Hout + (size_t)(r0 + lm)*128 + kof);
    const s16x8* ap1 = (const s16x8*)(Hout + (size_t)(r0 + 16 + lm)*128 + kof);
    #pragma unroll
    for (int kk = 0; kk < 4; kk++){ af0[kk] = ap0[kk*4]; af1[kk] = ap1[kk*4]; }
  }

  s16x8 bA[4], bB[4];
#define LOADB(dst, tl) { \
    const s16x8* bp_ = (const s16x8*)(WoutP + (size_t)((tl)*16 + lm)*128 + kof); \
    dst[0] = bp_[0]; dst[1] = bp_[4]; dst[2] = bp_[8]; dst[3] = bp_[12]; }

  // ---- pass 1: row sums of exp(logit), 80 tiles per wave ----
  float rs0[4] = {0,0,0,0}, rs1[4] = {0,0,0,0};
#define P1COMP(buf, tl) { \
    f32x4 a0_ = {0,0,0,0}, a1_ = {0,0,0,0}; \
    _Pragma("unroll") \
    for (int kk = 0; kk < 4; kk++){ \
      a0_ = __builtin_amdgcn_mfma_f32_16x16x32_bf16(af0[kk], buf[kk], a0_, 0, 0, 0); \
      a1_ = __builtin_amdgcn_mfma_f32_16x16x32_bf16(af1[kk], buf[kk], a1_, 0, 0, 0); } \
    float bo_ = boutP[(tl)*16 + lm]; \
    _Pragma("unroll") \
    for (int i = 0; i < 4; i++){ rs0[i] += __expf(a0_[i] + bo_); rs1[i] += __expf(a1_[i] + bo_); } }

  {
    int tl = w;
    LOADB(bA, tl);
    for (int it = 0; it < 39; it++){
      LOADB(bB, tl + 8);
      P1COMP(bA, tl);
      LOADB(bA, tl + 16);
      P1COMP(bB, tl + 8);
      tl += 16;
    }
    LOADB(bB, tl + 8);
    P1COMP(bA, tl);        // tile w + 624
    P1COMP(bB, tl + 8);    // tile w + 632
  }

  #pragma unroll
  for (int i = 0; i < 4; i++){
    float s0 = rs0[i], s1 = rs1[i];
    s0 += __shfl_xor(s0, 1); s0 += __shfl_xor(s0, 2); s0 += __shfl_xor(s0, 4); s0 += __shfl_xor(s0, 8);
    s1 += __shfl_xor(s1, 1); s1 += __shfl_xor(s1, 2); s1 += __shfl_xor(s1, 4); s1 += __shfl_xor(s1, 8);
    rs0[i] = s0; rs1[i] = s1;
  }
  if (lm == 0){
    #pragma unroll
    for (int i = 0; i < 4; i++){
      rs_l[w][lq*4 + i] = rs0[i];
      rs_l[w][16 + lq*4 + i] = rs1[i];
    }
  }
  __syncthreads();
  if (tid < 32){
    float s = rs_l[0][tid] + rs_l[1][tid] + rs_l[2][tid] + rs_l[3][tid]
            + rs_l[4][tid] + rs_l[5][tid] + rs_l[6][tid] + rs_l[7][tid];
    lse_l[tid] = logf(s);
  }
  __syncthreads();
  float ml0[4], ml1[4];
  #pragma unroll
  for (int i = 0; i < 4; i++){ ml0[i] = lse_l[lq*4 + i]; ml1[i] = lse_l[16 + lq*4 + i]; }

  // ---- pass 2 ----
#define P2COMP(buf, tl, q) { \
    f32x4 p0_ = {0,0,0,0}, p1_ = {0,0,0,0}; \
    _Pragma("unroll") \
    for (int kk = 0; kk < 4; kk++){ \
      p0_ = __builtin_amdgcn_mfma_f32_16x16x32_bf16(af0[kk], buf[kk], p0_, 0, 0, 0); \
      p1_ = __builtin_amdgcn_mfma_f32_16x16x32_bf16(af1[kk], buf[kk], p1_, 0, 0, 0); } \
    float bo_ = boutP[(tl)*16 + lm]; \
    int colq_ = ((q)*16) + lm; \
    _Pragma("unroll") \
    for (int i = 0; i < 4; i++){ \
      stage[(lq*4 + i)*516 + colq_]      = p0_[i] + bo_ - ml0[i]; \
      stage[(16 + lq*4 + i)*516 + colq_] = p1_[i] + bo_ - ml1[i]; } }

#define BAR() { asm volatile("s_waitcnt lgkmcnt(0)" ::: "memory"); __builtin_amdgcn_s_barrier(); }

  // chunk c: cols [c*512, c*512+512), tiles c*32 + w*4 + {0..3}
  LOADB(bA, w*4);   // chunk 0, q0
  for (int c = 0; c < 20; c++){
    int tb = c*32 + w*4;
    LOADB(bB, tb + 1);
    P2COMP(bA, tb + 0, w*4 + 0);
    LOADB(bA, tb + 2);
    P2COMP(bB, tb + 1, w*4 + 1);
    LOADB(bB, tb + 3);
    P2COMP(bA, tb + 2, w*4 + 2);
    if (c < 19) LOADB(bA, (c+1)*32 + w*4);
    P2COMP(bB, tb + 3, w*4 + 3);
    BAR();
    // write phase: 32 rows x 512 cols, dense 64-dword-per-wave nt-stores
    int vbase = c * 512;
    if (c < 19){
      #pragma unroll
      for (int j = 0; j < 32; j++){
        int e = j*512 + tid;
        int row = e >> 9, cc = e & 511;
        __builtin_nontemporal_store(stage[row*516 + cc],
            &out[obase + (size_t)row*10001u + (unsigned)(vbase + cc)]);
      }
    } else {
      #pragma unroll
      for (int j = 0; j < 32; j++){
        int e = j*512 + tid;
        int row = e >> 9, cc = e & 511;
        if (vbase + cc < 10001)
          __builtin_nontemporal_store(stage[row*516 + cc],
              &out[obase + (size_t)row*10001u + (unsigned)(vbase + cc)]);
      }
    }
    BAR();   // LDS reads done before next chunk overwrites stage
  }
}

// ---------------- host launcher ----------------
extern "C" void kernel_launch(void* const* d_in, const int* in_sizes, int n_in,
                              void* d_out, int out_size, void* d_ws, size_t ws_size,
                              hipStream_t stream)
{
  (void)in_sizes; (void)n_in; (void)out_size; (void)ws_size;
  const int*   inst    = (const int*)  d_in[0];
  const float* prevC   = (const float*)d_in[1];
  const float* finC    = (const float*)d_in[2];
  const float* tobj    = (const float*)d_in[3];
  const float* embW    = (const float*)d_in[4];
  const float* Wih     = (const float*)d_in[5];
  const float* Whh     = (const float*)d_in[6];
  const float* bih     = (const float*)d_in[7];
  const float* bhh     = (const float*)d_in[8];
  const float* Wout    = (const float*)d_in[9];
  const float* bout    = (const float*)d_in[10];
  const float* Wtgt    = (const float*)d_in[11];
  const float* btgt    = (const float*)d_in[12];
  const float* Wobj    = (const float*)d_in[13];
  const float* bobj    = (const float*)d_in[14];
  const float* ceWih   = (const float*)d_in[15];
  const float* ceWhh   = (const float*)d_in[16];
  const float* cebih   = (const float*)d_in[17];
  const float* cebhh   = (const float*)d_in[18];

  char* ws = (char*)d_ws;
  unsigned short* WoutP = (unsigned short*)(ws + 0);         // 10240*128*2 = 2,621,440
  float* boutP = (float*)(ws + 2621440);                     // 10240*4     = 40,960
  float* bsum  = (float*)(ws + 2662400);                     // 512*4       = 2,048
  float* tgt   = (float*)(ws + 2664448);                     // 256*64*4    = 65,536
  float* encP  = (float*)(ws + 2729984);                     // 256*64*4    = 65,536
  float* encF  = (float*)(ws + 2795520);                     // 256*64*4    = 65,536
  unsigned short* Hout = (unsigned short*)(ws + 2861056);    // 16384*128*2 = 4,194,304
  unsigned short* cePack = (unsigned short*)(ws + 7055360);  // 32768*2     = 65,536
  float* out = (float*)d_out;

  hipFuncSetAttribute((const void*)k_out,
                      hipFuncAttributeMaxDynamicSharedMemorySize, 66048);

  k_prep  <<<5354, 256, 0, stream>>>(Wout, bout, bih, bhh, tobj, Wtgt, btgt,
                                     ceWih, ceWhh, WoutP, boutP, bsum, tgt, cePack);
  k_canvas<<<512, 256, 0, stream>>>(prevC, finC, Wobj, bobj, cePack,
                                    cebih, cebhh, encP, encF);
  k_rec   <<<256, 512, 0, stream>>>(Whh, Wih, bsum, inst, embW, tgt, encP, encF, Hout);
  k_out   <<<512, 512, 66048, stream>>>(Hout, WoutP, boutP, out);
}

// Round 7
// 529.493 us; speedup vs baseline: 1.1900x; 1.1795x over previous
//
#include <hip/hip_runtime.h>
#include <stdint.h>

typedef __attribute__((ext_vector_type(4))) float f32x4;
typedef __attribute__((ext_vector_type(8))) short s16x8;
typedef __attribute__((ext_vector_type(8))) unsigned short us8;

__device__ __forceinline__ float bf2f(unsigned short u){
  union { unsigned int i; float f; } v; v.i = ((unsigned int)u) << 16; return v.f;
}
__device__ __forceinline__ unsigned short f2bf(float f){
  union { float f; unsigned int i; } v; v.f = f;
  unsigned int r = v.i + 0x7FFFu + ((v.i >> 16) & 1u);
  return (unsigned short)(r >> 16);
}
__device__ __forceinline__ float sigm(float x){ return 1.0f / (1.0f + __expf(-x)); }

// ---------------- K0: prep ----------------
#define NA (10240*128)
#define NB 10240
#define ND 512
#define NE (256*64)
#define NF 32768

__global__ void k_prep(const float* __restrict__ Wout, const float* __restrict__ bout,
                       const float* __restrict__ bih,  const float* __restrict__ bhh,
                       const float* __restrict__ tobj, const float* __restrict__ Wtgt,
                       const float* __restrict__ btgt,
                       const float* __restrict__ ceWih, const float* __restrict__ ceWhh,
                       unsigned short* __restrict__ WoutP, float* __restrict__ boutP,
                       float* __restrict__ bsum, float* __restrict__ tgt,
                       unsigned short* __restrict__ cePack)
{
  int tid = blockIdx.x * 256 + threadIdx.x;
  if (tid < NA){
    int vv = tid >> 7, k = tid & 127;
    float val = (vv < 10001) ? Wout[vv*128 + k] : 0.0f;
    WoutP[tid] = f2bf(val);
  } else if (tid < NA+NB){
    int vv = tid - NA;
    boutP[vv] = (vv < 10001) ? bout[vv] : -1e30f;
  } else if (tid < NA+NB+ND){
    int g = tid - NA - NB;
    bsum[g] = bih[g] + bhh[g];
  } else if (tid < NA+NB+ND+NE){
    int i = tid - NA - NB - ND; int b = i >> 6, j = i & 63;
    const float* to = tobj + b*4; const float* wt = Wtgt + j*4;
    tgt[i] = btgt[j] + to[0]*wt[0] + to[1]*wt[1] + to[2]*wt[2] + to[3]*wt[3];
  } else if (tid < NA+NB+ND+NE+NF){
    int i = tid - NA - NB - ND - NE;
    int half = i >> 14;
    int r = (i >> 6) & 255;
    int k = i & 63;
    int k8 = k >> 3;
    int slot = ((k8 ^ (r & 7)) << 3) | (k & 7);
    const float* src = half ? ceWhh : ceWih;
    cePack[half*16384 + r*64 + slot] = f2bf(src[r*64 + k]);
  }
}

// ---------------- K1: canvas encoder (25-step LSTM, H=64) ----------------
__global__ __launch_bounds__(256) void k_canvas(
    const float* __restrict__ prevC, const float* __restrict__ finC,
    const float* __restrict__ Wobj,  const float* __restrict__ bobj,
    const unsigned short* __restrict__ cePack,
    const float* __restrict__ cebih, const float* __restrict__ cebhh,
    float* __restrict__ encP, float* __restrict__ encF)
{
  __shared__ unsigned short wih[256*64] __attribute__((aligned(16)));
  __shared__ unsigned short whh[256*64] __attribute__((aligned(16)));
  __shared__ float seq[25*4];
  __shared__ float xb[64] __attribute__((aligned(16)));
  __shared__ float hb[2][64] __attribute__((aligned(16)));
  __shared__ float gates[256];
  __shared__ float wobj_s[256];
  __shared__ float bobj_s[64];
  __shared__ float bsum_ce[256];

  int tid = threadIdx.x;
  int b = blockIdx.x & 255;
  int which = blockIdx.x >> 8;
  const float* canvas = (which ? finC : prevC) + b*100;

  {
    const us8* cp = (const us8*)cePack;
    us8* wl = (us8*)wih;
    us8* hl = (us8*)whh;
    for (int i = tid; i < 2048; i += 256){
      wl[i] = cp[i];
      hl[i] = cp[2048 + i];
    }
  }
  wobj_s[tid] = Wobj[tid];
  if (tid < 64) bobj_s[tid] = bobj[tid];
  bsum_ce[tid] = cebih[tid] + cebhh[tid];
  if (tid < 64) hb[0][tid] = 0.0f;
  if (tid == 0){
    int pos = 0;
    for (int i = 0; i < 25; i++){
      float a0=canvas[i*4+0], a1=canvas[i*4+1], a2=canvas[i*4+2], a3=canvas[i*4+3];
      if (a0+a1+a2+a3 >= 0.0f){
        seq[pos*4+0]=a0; seq[pos*4+1]=a1; seq[pos*4+2]=a2; seq[pos*4+3]=a3; pos++;
      }
    }
    for (; pos < 25; pos++){
      seq[pos*4+0]=-1.0f; seq[pos*4+1]=-1.0f; seq[pos*4+2]=-1.0f; seq[pos*4+3]=-1.0f;
    }
  }
  __syncthreads();

  float creg = 0.0f;
  int cur = 0;
  const float4* x4 = (const float4*)xb;

  for (int t = 0; t < 25; t++){
    if (tid < 64){
      float a = bobj_s[tid];
      a += wobj_s[tid*4+0]*seq[t*4+0] + wobj_s[tid*4+1]*seq[t*4+1]
         + wobj_s[tid*4+2]*seq[t*4+2] + wobj_s[tid*4+3]*seq[t*4+3];
      xb[tid] = a;
    }
    __syncthreads();
    float acc = bsum_ce[tid];
    const float4* h4 = (const float4*)hb[cur];
    int rowoff = tid*64;
    int sw = tid & 7;
    #pragma unroll
    for (int k8 = 0; k8 < 8; k8++){
      int slot = ((k8 ^ sw) * 8);
      us8 w1 = *reinterpret_cast<const us8*>(&wih[rowoff + slot]);
      us8 w2 = *reinterpret_cast<const us8*>(&whh[rowoff + slot]);
      float4 xa = x4[2*k8], xc = x4[2*k8+1];
      float4 ha = h4[2*k8], hc = h4[2*k8+1];
      acc += bf2f(w1[0])*xa.x + bf2f(w1[1])*xa.y + bf2f(w1[2])*xa.z + bf2f(w1[3])*xa.w;
      acc += bf2f(w1[4])*xc.x + bf2f(w1[5])*xc.y + bf2f(w1[6])*xc.z + bf2f(w1[7])*xc.w;
      acc += bf2f(w2[0])*ha.x + bf2f(w2[1])*ha.y + bf2f(w2[2])*ha.z + bf2f(w2[3])*ha.w;
      acc += bf2f(w2[4])*hc.x + bf2f(w2[5])*hc.y + bf2f(w2[6])*hc.z + bf2f(w2[7])*hc.w;
    }
    gates[tid] = acc;
    __syncthreads();
    if (tid < 64){
      float i_ = sigm(gates[tid]);
      float f_ = sigm(gates[64+tid]);
      float g_ = tanhf(gates[128+tid]);
      float o_ = sigm(gates[192+tid]);
      creg = f_*creg + i_*g_;
      hb[cur^1][tid] = o_ * tanhf(creg);
    }
    __syncthreads();
    cur ^= 1;
  }
  if (tid < 64){
    (which ? encF : encP)[b*64 + tid] = hb[cur][tid];
  }
}

// ---------------- K2: main LSTM recurrence (66 steps, H=128), Wih fused -------
// Hout layout: row r = b*64 + (s-2), r*128 + g
__global__ __launch_bounds__(512, 2) void k_rec(
    const float* __restrict__ Whh, const float* __restrict__ Wih,
    const float* __restrict__ bsum, const int* __restrict__ inst,
    const float* __restrict__ embW, const float* __restrict__ tgt,
    const float* __restrict__ encP, const float* __restrict__ encF,
    unsigned short* __restrict__ Hout)
{
  int b = blockIdx.x;
  int g = threadIdx.x;
  __shared__ float xb[2][64] __attribute__((aligned(16)));
  __shared__ float hb[2][128] __attribute__((aligned(16)));
  __shared__ float gates[512];

  float wreg[128];
  float ureg[64];
  {
    const float4* wrow = (const float4*)(Whh + g*128);
    #pragma unroll
    for (int k4 = 0; k4 < 32; k4++){
      float4 w = wrow[k4];
      wreg[4*k4+0]=w.x; wreg[4*k4+1]=w.y; wreg[4*k4+2]=w.z; wreg[4*k4+3]=w.w;
    }
    const float4* urow = (const float4*)(Wih + g*64);
    #pragma unroll
    for (int k4 = 0; k4 < 16; k4++){
      float4 w = urow[k4];
      ureg[4*k4+0]=w.x; ureg[4*k4+1]=w.y; ureg[4*k4+2]=w.z; ureg[4*k4+3]=w.w;
    }
  }
  float bz = bsum[g];
  float creg = 0.0f;
  if (g < 128) hb[0][g] = 0.0f;
  if (g < 64)  xb[0][g] = encP[b*64+g] + encF[b*64+g];
  int cur = 0;
  __syncthreads();

  for (int s = 0; s < 66; s++){
    float a0 = bz, a1 = 0.0f, a2 = 0.0f, a3 = 0.0f;
    const float4* h4 = (const float4*)hb[cur];
    const float4* x4 = (const float4*)xb[cur];
    #pragma unroll
    for (int k4 = 0; k4 < 32; k4 += 4){
      float4 h0 = h4[k4], h1 = h4[k4+1], h2 = h4[k4+2], h3 = h4[k4+3];
      a0 += wreg[4*k4+0]*h0.x + wreg[4*k4+1]*h0.y + wreg[4*k4+2]*h0.z + wreg[4*k4+3]*h0.w;
      a1 += wreg[4*k4+4]*h1.x + wreg[4*k4+5]*h1.y + wreg[4*k4+6]*h1.z + wreg[4*k4+7]*h1.w;
      a2 += wreg[4*k4+8]*h2.x + wreg[4*k4+9]*h2.y + wreg[4*k4+10]*h2.z + wreg[4*k4+11]*h2.w;
      a3 += wreg[4*k4+12]*h3.x + wreg[4*k4+13]*h3.y + wreg[4*k4+14]*h3.z + wreg[4*k4+15]*h3.w;
    }
    #pragma unroll
    for (int k4 = 0; k4 < 16; k4 += 4){
      float4 x0 = x4[k4], x1 = x4[k4+1], x2 = x4[k4+2], x3 = x4[k4+3];
      a0 += ureg[4*k4+0]*x0.x + ureg[4*k4+1]*x0.y + ureg[4*k4+2]*x0.z + ureg[4*k4+3]*x0.w;
      a1 += ureg[4*k4+4]*x1.x + ureg[4*k4+5]*x1.y + ureg[4*k4+6]*x1.z + ureg[4*k4+7]*x1.w;
      a2 += ureg[4*k4+8]*x2.x + ureg[4*k4+9]*x2.y + ureg[4*k4+10]*x2.z + ureg[4*k4+11]*x2.w;
      a3 += ureg[4*k4+12]*x3.x + ureg[4*k4+13]*x3.y + ureg[4*k4+14]*x3.z + ureg[4*k4+15]*x3.w;
    }
    gates[g] = (a0 + a1) + (a2 + a3);
    __syncthreads();
    if (g < 128){
      float i_ = sigm(gates[g]);
      float f_ = sigm(gates[128+g]);
      float g_ = tanhf(gates[256+g]);
      float o_ = sigm(gates[384+g]);
      creg = f_*creg + i_*g_;
      float h = o_ * tanhf(creg);
      hb[cur^1][g] = h;
      if (s >= 2) Hout[((size_t)(b*64 + (s-2)))*128 + g] = f2bf(h);
    } else if (g < 192 && s < 65){
      int l = g - 128;
      float v;
      if (s + 1 == 1) v = tgt[b*64 + l];
      else { int tok = inst[b*65 + (s - 1)]; v = embW[tok*64 + l]; }
      xb[cur^1][l] = v;
    }
    __syncthreads();
    cur ^= 1;
  }
}

// ---------------- K3: logits GEMM + log_softmax ----------------
// 256 blocks x 64 consecutive rows. 8 waves split columns (wave w owns cols
// w*16 mod 128 pattern). Each wave: 4 MFMA chains (64 rows) per B-tile ->
// 16 MFMA per 4 loads. 3-buffer register rotation, prefetch depth 2.
// Pass 2: 20 chunks of 512 cols; stage [64][520] f32 in 133KB dyn LDS;
// write phase row=j col=tid -> 2KB contiguous nt-stores per row.
__global__ __launch_bounds__(512, 2) void k_out(
    const unsigned short* __restrict__ Hout, const unsigned short* __restrict__ WoutP,
    const float* __restrict__ boutP, float* __restrict__ out)
{
  extern __shared__ float stage[];   // [64][520] floats = 133120 B
  __shared__ float rs_l[8][64];
  __shared__ float lse_l[64];

  int blk = blockIdx.x;
  int r0 = blk * 64;
  int tid = threadIdx.x;
  int w = tid >> 6;
  int l = tid & 63;
  int lm = l & 15;
  int lq = l >> 4;
  int kof = lq * 8;
  size_t obase = (size_t)r0 * 10001u;

  // A fragments: 4 chains x 16 rows, K=128
  s16x8 af[4][4];
  #pragma unroll
  for (int c = 0; c < 4; c++){
    const s16x8* ap = (const s16x8*)(Hout + (size_t)(r0 + c*16 + lm)*128 + kof);
    #pragma unroll
    for (int kk = 0; kk < 4; kk++) af[c][kk] = ap[kk*4];
  }

  s16x8 b0[4], b1[4], b2[4];
#define LOADB(dst, tl) { \
    const s16x8* bp_ = (const s16x8*)(WoutP + (size_t)((tl)*16 + lm)*128 + kof); \
    dst[0] = bp_[0]; dst[1] = bp_[4]; dst[2] = bp_[8]; dst[3] = bp_[12]; }

  // ---- pass 1: row sums of exp(logit), tiles w, w+8, ..., w+632 ----
  float rs[4][4] = {};
#define P1C(buf, tl) { \
    f32x4 a0_ = {0,0,0,0}, a1_ = {0,0,0,0}, a2_ = {0,0,0,0}, a3_ = {0,0,0,0}; \
    _Pragma("unroll") \
    for (int kk = 0; kk < 4; kk++){ \
      a0_ = __builtin_amdgcn_mfma_f32_16x16x32_bf16(af[0][kk], buf[kk], a0_, 0, 0, 0); \
      a1_ = __builtin_amdgcn_mfma_f32_16x16x32_bf16(af[1][kk], buf[kk], a1_, 0, 0, 0); \
      a2_ = __builtin_amdgcn_mfma_f32_16x16x32_bf16(af[2][kk], buf[kk], a2_, 0, 0, 0); \
      a3_ = __builtin_amdgcn_mfma_f32_16x16x32_bf16(af[3][kk], buf[kk], a3_, 0, 0, 0); } \
    float bo_ = boutP[(tl)*16 + lm]; \
    _Pragma("unroll") \
    for (int i = 0; i < 4; i++){ \
      rs[0][i] += __expf(a0_[i] + bo_); rs[1][i] += __expf(a1_[i] + bo_); \
      rs[2][i] += __expf(a2_[i] + bo_); rs[3][i] += __expf(a3_[i] + bo_); } }

  {
    int tl = w;
    LOADB(b0, tl); LOADB(b1, tl + 8);
    for (int p = 0; p < 26; p++){
      LOADB(b2, tl + 16); P1C(b0, tl);
      LOADB(b0, tl + 24); P1C(b1, tl + 8);
      LOADB(b1, tl + 32); P1C(b2, tl + 16);
      tl += 24;
    }
    P1C(b0, tl);       // w + 624
    P1C(b1, tl + 8);   // w + 632
  }

  #pragma unroll
  for (int c = 0; c < 4; c++){
    #pragma unroll
    for (int i = 0; i < 4; i++){
      float s = rs[c][i];
      s += __shfl_xor(s, 1); s += __shfl_xor(s, 2);
      s += __shfl_xor(s, 4); s += __shfl_xor(s, 8);
      rs[c][i] = s;
    }
  }
  if (lm == 0){
    #pragma unroll
    for (int c = 0; c < 4; c++)
      #pragma unroll
      for (int i = 0; i < 4; i++)
        rs_l[w][c*16 + lq*4 + i] = rs[c][i];
  }

  // issue pass-2 preloads before the LSE barriers (hide latency under them)
#define T2(c,q) ((c)*32 + w*4 + (q))
  LOADB(b0, T2(0,0)); LOADB(b1, T2(0,1));

#define BAR() { asm volatile("s_waitcnt lgkmcnt(0)" ::: "memory"); __builtin_amdgcn_s_barrier(); }

  BAR();
  if (tid < 64){
    float s = rs_l[0][tid] + rs_l[1][tid] + rs_l[2][tid] + rs_l[3][tid]
            + rs_l[4][tid] + rs_l[5][tid] + rs_l[6][tid] + rs_l[7][tid];
    lse_l[tid] = logf(s);
  }
  BAR();
  float ml[4][4];
  #pragma unroll
  for (int c = 0; c < 4; c++)
    #pragma unroll
    for (int i = 0; i < 4; i++)
      ml[c][i] = lse_l[c*16 + lq*4 + i];

  // ---- pass 2 ----
#define P2C(buf, tl, q) { \
    f32x4 a0_ = {0,0,0,0}, a1_ = {0,0,0,0}, a2_ = {0,0,0,0}, a3_ = {0,0,0,0}; \
    _Pragma("unroll") \
    for (int kk = 0; kk < 4; kk++){ \
      a0_ = __builtin_amdgcn_mfma_f32_16x16x32_bf16(af[0][kk], buf[kk], a0_, 0, 0, 0); \
      a1_ = __builtin_amdgcn_mfma_f32_16x16x32_bf16(af[1][kk], buf[kk], a1_, 0, 0, 0); \
      a2_ = __builtin_amdgcn_mfma_f32_16x16x32_bf16(af[2][kk], buf[kk], a2_, 0, 0, 0); \
      a3_ = __builtin_amdgcn_mfma_f32_16x16x32_bf16(af[3][kk], buf[kk], a3_, 0, 0, 0); } \
    float bo_ = boutP[(tl)*16 + lm]; \
    int colq_ = (w*4 + (q))*16 + lm; \
    _Pragma("unroll") \
    for (int i = 0; i < 4; i++){ \
      stage[(0*16 + lq*4 + i)*520 + colq_] = a0_[i] + bo_ - ml[0][i]; \
      stage[(1*16 + lq*4 + i)*520 + colq_] = a1_[i] + bo_ - ml[1][i]; \
      stage[(2*16 + lq*4 + i)*520 + colq_] = a2_[i] + bo_ - ml[2][i]; \
      stage[(3*16 + lq*4 + i)*520 + colq_] = a3_[i] + bo_ - ml[3][i]; } }

#define WPHASE(c) { \
    int vbase_ = (c)*512; \
    if ((c) < 19){ \
      _Pragma("unroll 4") \
      for (int j = 0; j < 64; j++){ \
        __builtin_nontemporal_store(stage[j*520 + tid], \
            &out[obase + (size_t)j*10001u + (unsigned)(vbase_ + tid)]); } \
    } else { \
      if (tid < 273){ \
        _Pragma("unroll 4") \
        for (int j = 0; j < 64; j++){ \
          __builtin_nontemporal_store(stage[j*520 + tid], \
              &out[obase + (size_t)j*10001u + (unsigned)(vbase_ + tid)]); } } } }

#define CHUNK(ba,bb,bc,c) { \
    LOADB(bc, T2(c,2));   P2C(ba, T2(c,0), 0); \
    LOADB(ba, T2(c,3));   P2C(bb, T2(c,1), 1); \
    LOADB(bb, T2((c)+1,0)); P2C(bc, T2(c,2), 2); \
    LOADB(bc, T2((c)+1,1)); P2C(ba, T2(c,3), 3); \
    BAR(); WPHASE(c); BAR(); }

  for (int cb = 0; cb < 18; cb += 3){
    CHUNK(b0, b1, b2, cb);
    CHUNK(b1, b2, b0, cb + 1);
    CHUNK(b2, b0, b1, cb + 2);
  }
  CHUNK(b0, b1, b2, 18);           // leaves T2(19,0) in b1, T2(19,1) in b2
  // final chunk 19
  LOADB(b0, T2(19,2)); P2C(b1, T2(19,0), 0);
  LOADB(b1, T2(19,3)); P2C(b2, T2(19,1), 1);
  P2C(b0, T2(19,2), 2);
  P2C(b1, T2(19,3), 3);
  BAR();
  WPHASE(19);
}

// ---------------- host launcher ----------------
extern "C" void kernel_launch(void* const* d_in, const int* in_sizes, int n_in,
                              void* d_out, int out_size, void* d_ws, size_t ws_size,
                              hipStream_t stream)
{
  (void)in_sizes; (void)n_in; (void)out_size; (void)ws_size;
  const int*   inst    = (const int*)  d_in[0];
  const float* prevC   = (const float*)d_in[1];
  const float* finC    = (const float*)d_in[2];
  const float* tobj    = (const float*)d_in[3];
  const float* embW    = (const float*)d_in[4];
  const float* Wih     = (const float*)d_in[5];
  const float* Whh     = (const float*)d_in[6];
  const float* bih     = (const float*)d_in[7];
  const float* bhh     = (const float*)d_in[8];
  const float* Wout    = (const float*)d_in[9];
  const float* bout    = (const float*)d_in[10];
  const float* Wtgt    = (const float*)d_in[11];
  const float* btgt    = (const float*)d_in[12];
  const float* Wobj    = (const float*)d_in[13];
  const float* bobj    = (const float*)d_in[14];
  const float* ceWih   = (const float*)d_in[15];
  const float* ceWhh   = (const float*)d_in[16];
  const float* cebih   = (const float*)d_in[17];
  const float* cebhh   = (const float*)d_in[18];

  char* ws = (char*)d_ws;
  unsigned short* WoutP = (unsigned short*)(ws + 0);         // 10240*128*2 = 2,621,440
  float* boutP = (float*)(ws + 2621440);                     // 10240*4     = 40,960
  float* bsum  = (float*)(ws + 2662400);                     // 512*4       = 2,048
  float* tgt   = (float*)(ws + 2664448);                     // 256*64*4    = 65,536
  float* encP  = (float*)(ws + 2729984);                     // 256*64*4    = 65,536
  float* encF  = (float*)(ws + 2795520);                     // 256*64*4    = 65,536
  unsigned short* Hout = (unsigned short*)(ws + 2861056);    // 16384*128*2 = 4,194,304
  unsigned short* cePack = (unsigned short*)(ws + 7055360);  // 32768*2     = 65,536
  float* out = (float*)d_out;

  hipFuncSetAttribute((const void*)k_out,
                      hipFuncAttributeMaxDynamicSharedMemorySize, 133120);

  k_prep  <<<5354, 256, 0, stream>>>(Wout, bout, bih, bhh, tobj, Wtgt, btgt,
                                     ceWih, ceWhh, WoutP, boutP, bsum, tgt, cePack);
  k_canvas<<<512, 256, 0, stream>>>(prevC, finC, Wobj, bobj, cePack,
                                    cebih, cebhh, encP, encF);
  k_rec   <<<256, 512, 0, stream>>>(Whh, Wih, bsum, inst, embW, tgt, encP, encF, Hout);
  k_out   <<<256, 512, 133120, stream>>>(Hout, WoutP, boutP, out);
}